// Round 11
// baseline (1119.733 us; speedup 1.0000x reference)
//
#include <hip/hip_runtime.h>
#include <hip/hip_bf16.h>
#include <cstdint>

#define NNODES 20000
#define NEDGES 640000
#define ETOT   (NEDGES + NNODES)
#define NGROUP 64
#define HC     256
#define DOUT   32
#define EBLK   5120                     // edges per CSR slice (divides NEDGES)
#define NBLK   125                      // hist/scatter slices
#define CBLK   79                       // ceil(NNODES/256) node blocks
#define GBLK   1250                     // gemm tiles (16 rows each)
#define G2BLK  625                      // gemm2 blocks (2 tiles each)
#define ABLK   2500                     // agg blocks (4 waves = 4 nodes/stride-step)

typedef short bf16x8 __attribute__((ext_vector_type(8)));
typedef short s16x4  __attribute__((ext_vector_type(4)));
typedef float f32x4  __attribute__((ext_vector_type(4)));
typedef float f32x2  __attribute__((ext_vector_type(2)));
typedef int   s32x4  __attribute__((ext_vector_type(4)));
typedef unsigned int u32x4 __attribute__((ext_vector_type(4)));

__device__ __forceinline__ float bs2f(short v) {
    union { unsigned int u; float f; } c; c.u = ((unsigned int)(unsigned short)v) << 16; return c.f;
}
__device__ __forceinline__ short f2bs(float v) {
    __hip_bfloat16 b = __float2bfloat16(v);
    union { __hip_bfloat16 b; short s; } u; u.b = b; return u.s;
}
__device__ __forceinline__ float ldf(const void* __restrict__ p, size_t i, int bf) {
    return bf ? __bfloat162float(((const __hip_bfloat16*)p)[i]) : ((const float*)p)[i];
}
__device__ __forceinline__ int ld_idx(const int* __restrict__ p, size_t i, int f64) {
    return f64 ? p[2 * i] : p[i];
}
// monotone float<->uint map for atomicMax on floats
__device__ __forceinline__ unsigned enc_f(float f) {
    unsigned u = __float_as_uint(f);
    return (u >> 31) ? ~u : (u | 0x80000000u);
}
__device__ __forceinline__ float dec_f(unsigned e) {
    return (e >> 31) ? __uint_as_float(e & 0x7FFFFFFFu) : __uint_as_float(~e);
}
// local flag probes (identical result in every block -> no flag round-trip)
__device__ __forceinline__ int probe_edge64(const int* __restrict__ ei) {
    int l = threadIdx.x & 63;
    int zeros = 0;
#pragma unroll
    for (int r = 0; r < 4; r++)
        zeros += __popcll(__ballot(ei[2 * (r * 64 + l) + 1] == 0));
    return (zeros > 200) ? 1 : 0;
}
__device__ __forceinline__ int probe_xbf(const unsigned int* __restrict__ xw) {
    int l = threadIdx.x & 63;
    int ones = 0;
#pragma unroll
    for (int r = 0; r < 4; r++)
        ones += __popcll(__ballot((xw[r * 64 + l] >> 14) & 1));
    return (ones < 64) ? 1 : 0;
}
// ---- intra-launch producer/consumer handshake (decoupled-lookback pattern) ----
// signal: all threads fence (device-visible stores) -> barrier -> one atomicAdd.
__device__ __forceinline__ void signal_done(int* ctr) {
    __threadfence();
    __syncthreads();
    if (threadIdx.x == 0) atomicAdd(ctr, 1);
}
// wait: lane-0 spins with s_sleep backoff; then block-wide acquire.
__device__ __forceinline__ void spin_wait(int* ctr, int target) {
    if (threadIdx.x == 0) {
        while (__hip_atomic_load(ctr, __ATOMIC_RELAXED, __HIP_MEMORY_SCOPE_AGENT) < target)
            __builtin_amdgcn_s_sleep(8);
    }
    __syncthreads();
    __threadfence();
}

// ================= L1 setup: hist slices + weight transposes + inits =================
__global__ __launch_bounds__(256) void k_setup(const unsigned int* __restrict__ xw,
                                               const int* __restrict__ ei,
                                               const int* __restrict__ bat,
                                               const void* __restrict__ W1, const void* __restrict__ W2,
                                               __hip_bfloat16* __restrict__ Wt1,
                                               __hip_bfloat16* __restrict__ Wt2,
                                               int* __restrict__ H,
                                               float* __restrict__ sx, int* __restrict__ cnt,
                                               unsigned* __restrict__ gp2, int* __restrict__ sy) {
    __shared__ int hl[NNODES];  // 80 KB
    int t = threadIdx.x, b = blockIdx.x;
    if (b < NBLK) {
        int f = probe_edge64(ei);
        s32x4* hl4 = reinterpret_cast<s32x4*>(hl);
        for (int i = t; i < NNODES / 4; i += 256) hl4[i] = (s32x4){0, 0, 0, 0};
        __syncthreads();
        int s0 = b * EBLK;
        if (f) {
            const int* d64 = ei + 2 * NEDGES;   // low words at d64[2*i]
            for (int i0 = s0; i0 < s0 + EBLK; i0 += 512) {
                int i = i0 + 2 * t;
                s32x4 v = *reinterpret_cast<const s32x4*>(d64 + 2 * (size_t)i);
                atomicAdd(&hl[v[0]], 1);
                atomicAdd(&hl[v[2]], 1);
            }
        } else {
            const int* d32 = ei + NEDGES;
            for (int i0 = s0; i0 < s0 + EBLK; i0 += 1024) {
                int i = i0 + 4 * t;
                s32x4 v = *reinterpret_cast<const s32x4*>(d32 + i);
                atomicAdd(&hl[v[0]], 1); atomicAdd(&hl[v[1]], 1);
                atomicAdd(&hl[v[2]], 1); atomicAdd(&hl[v[3]], 1);
            }
        }
        __syncthreads();
        s32x4* Hb4 = reinterpret_cast<s32x4*>(H + (size_t)b * NNODES);
        for (int i = t; i < NNODES / 4; i += 256) Hb4[i] = hl4[i];
    } else {
        int bf = probe_xbf(xw);
        int i = (b - NBLK) * 256 + t;  // 131072
        int which = i >> 16;
        int j = i & 65535;
        int k = j >> 8, n = j & 255;
        const void* W = which ? W2 : W1;
        __hip_bfloat16* Wt = which ? Wt2 : Wt1;
        Wt[(size_t)n * 256 + k] = __float2bfloat16(ldf(W, (size_t)k * 256 + n, bf));
        if (b == NBLK) {
            for (int q = t; q < NGROUP * HC; q += 256) sx[q] = 0.f;
            if (t < 256) gp2[t] = 0x007FFFFFu;   // enc(-inf), 4 heads x 64 slots
            if (t < 8) sy[t] = 0;                // handshake counters
            // per-group node counts via LDS histogram (batch sorted; order free)
            int f = probe_edge64(ei);
            if (t < NGROUP) hl[t] = 0;
            __syncthreads();
            for (int r = t; r < NNODES; r += 256) atomicAdd(&hl[ld_idx(bat, r, f)], 1);
            __syncthreads();
            if (t < NGROUP) cnt[t] = hl[t];
        }
    }
}

// one 16-row GEMM tile (4 waves; wave w = head w's 64 cols); fused es/ed scores;
// per-head max -> scattered atomicMax tree gp2[w*64 + tile&63].
__device__ __forceinline__ void dev_gemm(int tile, const void* __restrict__ A,
                                         const __hip_bfloat16* __restrict__ Bt,
                                         __hip_bfloat16* __restrict__ Hout,
                                         const void* __restrict__ a_src, const void* __restrict__ a_dst,
                                         float* __restrict__ es4, float* __restrict__ ed4,
                                         unsigned* __restrict__ gp2, int bf, int abf,
                                         u32x4* hst4) {
    int w    = threadIdx.x >> 6;
    int lane = threadIdx.x & 63;
    int mr   = lane & 15;
    int quad = lane >> 4;
    int r0   = tile * 16;
    f32x4 acc[4];
#pragma unroll
    for (int j = 0; j < 4; j++) acc[j] = (f32x4){0.f, 0.f, 0.f, 0.f};
    size_t rowoff = (size_t)(r0 + mr) * HC;
    const __hip_bfloat16* Btw = Bt + (size_t)w * 64 * HC;
    for (int kk = 0; kk < HC; kk += 32) {
        bf16x8 a;
        if (abf) {
            a = *reinterpret_cast<const bf16x8*>((const __hip_bfloat16*)A + rowoff + kk + quad * 8);
        } else {
            const float* af = (const float*)A + rowoff + kk + quad * 8;
            f32x4 lo = *reinterpret_cast<const f32x4*>(af);
            f32x4 hi = *reinterpret_cast<const f32x4*>(af + 4);
#pragma unroll
            for (int ii = 0; ii < 4; ii++) { a[ii] = f2bs(lo[ii]); a[ii + 4] = f2bs(hi[ii]); }
        }
#pragma unroll
        for (int j = 0; j < 4; j++) {
            bf16x8 b = *reinterpret_cast<const bf16x8*>(Btw + (size_t)(j * 16 + mr) * HC + kk + quad * 8);
            acc[j] = __builtin_amdgcn_mfma_f32_16x16x32_bf16(a, b, acc[j], 0, 0, 0);
        }
    }
    short* hst = reinterpret_cast<short*>(hst4);
#pragma unroll
    for (int j = 0; j < 4; j++)
#pragma unroll
        for (int r = 0; r < 4; r++)
            hst[(quad * 4 + r) * HC + w * 64 + j * 16 + mr] = f2bs(acc[j][r]);
    float ps[4] = {0.f, 0.f, 0.f, 0.f}, pd[4] = {0.f, 0.f, 0.f, 0.f};
#pragma unroll
    for (int j = 0; j < 4; j++) {
        float asv = ldf(a_src, (size_t)(w * 64 + j * 16 + mr), bf);
        float adv = ldf(a_dst, (size_t)(w * 64 + j * 16 + mr), bf);
#pragma unroll
        for (int r = 0; r < 4; r++) {
            ps[r] = fmaf(acc[j][r], asv, ps[r]);
            pd[r] = fmaf(acc[j][r], adv, pd[r]);
        }
    }
#pragma unroll
    for (int o = 1; o < 16; o <<= 1)
#pragma unroll
        for (int r = 0; r < 4; r++) {
            ps[r] += __shfl_xor(ps[r], o);
            pd[r] += __shfl_xor(pd[r], o);
        }
    float pm = fmaxf(fmaxf(ps[0], ps[1]), fmaxf(ps[2], ps[3]));
    pm = fmaxf(pm, __shfl_xor(pm, 16));
    pm = fmaxf(pm, __shfl_xor(pm, 32));
    if (lane == 0) atomicMax(&gp2[w * 64 + (tile & 63)], enc_f(pm));
    if (mr == 0)
#pragma unroll
        for (int r = 0; r < 4; r++) {
            int row = r0 + quad * 4 + r;
            es4[(size_t)row * 4 + w] = ps[r];
            ed4[(size_t)row * 4 + w] = pd[r];
        }
    __syncthreads();
    u32x4* dst = reinterpret_cast<u32x4*>((short*)Hout + (size_t)r0 * HC);
    dst[threadIdx.x]       = hst4[threadIdx.x];
    dst[threadIdx.x + 256] = hst4[threadIdx.x + 256];
    __syncthreads();  // hst4 safe for reuse (multi-tile loops)
}

// ================= L2: colsum+base (handshake) || scatter (waits) || gemm-L1 ===========
// Scatter uses GLOBAL atomics on its private H row -> zero LDS -> gemm keeps 8 blocks/CU.
__global__ __launch_bounds__(256) void k_p2(const void* __restrict__ x,
                                            const int* __restrict__ ei,
                                            int* __restrict__ H, int* __restrict__ bsum,
                                            int* __restrict__ off, int* __restrict__ csr,
                                            const __hip_bfloat16* __restrict__ Wt1,
                                            __hip_bfloat16* __restrict__ hb,
                                            const void* __restrict__ as1, const void* __restrict__ ad1,
                                            float* __restrict__ es, float* __restrict__ ed,
                                            unsigned* __restrict__ gp2, int* __restrict__ sy) {
    __shared__ int smem[2048];  // 8 KB: gemm hst4 / cb scratch
    int bid = blockIdx.x, t = threadIdx.x;
    if (bid < CBLK) {
        // ---- colsum (deg kept in registers) ----
        int n = bid * 256 + t;
        int lane = t & 63, w = t >> 6;
        int d = 0;
        if (n < NNODES) {
#pragma unroll 5
            for (int b = 0; b < NBLK; b++) d += H[(size_t)b * NNODES + n];
            d += 1;  // self-loop
        }
        int r = d;
#pragma unroll
        for (int o = 1; o < 64; o <<= 1) r += __shfl_xor(r, o);
        if (lane == 0) smem[w] = r;
        __syncthreads();
        if (t == 0) bsum[bid] = smem[0] + smem[1] + smem[2] + smem[3];
        signal_done(&sy[0]);
        spin_wait(&sy[0], CBLK);
        // ---- base ----
        int sc = d;
#pragma unroll
        for (int o = 1; o < 64; o <<= 1) {
            int u = __shfl_up(sc, o);
            if (lane >= o) sc += u;
        }
        if (lane == 63) smem[w] = sc;
        if (w == 0) {  // exclusive prefix of block sums
            int v = (lane < bid) ? bsum[lane] : 0;
            if (lane + 64 < bid) v += bsum[lane + 64];
#pragma unroll
            for (int o = 1; o < 64; o <<= 1) v += __shfl_xor(v, o);
            if (lane == 0) smem[4] = v;
        }
        __syncthreads();
        int woff = 0;
        for (int i = 0; i < w; i++) woff += smem[i];
        int excl = woff + sc - d;
        if (bid == 0 && t == 0) off[NNODES] = ETOT;
        if (n < NNODES) {
            int o0 = smem[4] + excl;
            off[n] = o0;
            csr[o0] = n;          // self-loop first
            int run = o0 + 1;
#pragma unroll 5
            for (int b = 0; b < NBLK; b++) {
                size_t idx = (size_t)b * NNODES + n;
                int tt = H[idx];
                H[idx] = run;
                run += tt;
            }
        }
        signal_done(&sy[1]);
    } else if (bid < CBLK + NBLK) {
        // ---- scatter: global atomics on private H row (no LDS) ----
        int b = bid - CBLK;
        int f = probe_edge64(ei);
        spin_wait(&sy[1], CBLK);
        int* Hb = H + (size_t)b * NNODES;
        int s0 = b * EBLK;
        if (f) {
            const int* d64 = ei + 2 * NEDGES;
            for (int i0 = s0; i0 < s0 + EBLK; i0 += 512) {
                int i = i0 + 2 * t;
                s32x4 sv = *reinterpret_cast<const s32x4*>(ei + 2 * (size_t)i);
                s32x4 dv = *reinterpret_cast<const s32x4*>(d64 + 2 * (size_t)i);
                int p0 = atomicAdd(&Hb[dv[0]], 1); csr[p0] = sv[0];
                int p1 = atomicAdd(&Hb[dv[2]], 1); csr[p1] = sv[2];
            }
        } else {
            const int* d32 = ei + NEDGES;
            for (int i0 = s0; i0 < s0 + EBLK; i0 += 1024) {
                int i = i0 + 4 * t;
                s32x4 sv = *reinterpret_cast<const s32x4*>(ei + i);
                s32x4 dv = *reinterpret_cast<const s32x4*>(d32 + i);
#pragma unroll
                for (int k = 0; k < 4; k++) {
                    int p = atomicAdd(&Hb[dv[k]], 1); csr[p] = sv[k];
                }
            }
        }
    } else {
        // ---- gemm layer-1 (independent of CSR) ----
        int bf = probe_xbf((const unsigned int*)x);
        dev_gemm(bid - (CBLK + NBLK), x, Wt1, hb, as1, ad1, es, ed, gp2, bf, bf,
                 (u32x4*)smem);
    }
}

// fused bound-max softmax + aggregation (identical math to R10)
__device__ __forceinline__ void dev_agg(int nb0, const __hip_bfloat16* __restrict__ Hb,
                                        const float* __restrict__ es4, const float* __restrict__ ed4,
                                        const void* __restrict__ bias,
                                        const int* __restrict__ off, const int* __restrict__ csr,
                                        const unsigned* __restrict__ gp2, int bf,
                                        __hip_bfloat16* __restrict__ out, int* smem) {
    int wv = threadIdx.x >> 6;
    int l  = threadIdx.x & 63;
    int half = l >> 5;
    int hl   = l & 31;
    int hd8  = hl >> 3;
    float* pw = (float*)smem + wv * 256;   // [head][edge] weights, this wave
    int*   sw = smem + 1024 + wv * 64;     // edge src indices, this wave
    float* gm_s = (float*)(smem + 1280);
    {   // cheap gmax: 64 lanes read head wv's 64 slots
        float m = dec_f(gp2[wv * 64 + l]);
#pragma unroll
        for (int o = 32; o; o >>= 1) m = fmaxf(m, __shfl_xor(m, o));
        if (l == 0) gm_s[wv] = m;
    }
    __syncthreads();
    f32x4 gm = (f32x4){gm_s[0], gm_s[1], gm_s[2], gm_s[3]};
    for (int n = nb0 + wv; n < NNODES; n += 10000) {
        int base = off[n], deg = off[n + 1] - base;
        f32x4 edv = *reinterpret_cast<const f32x4*>(ed4 + (size_t)n * 4);
        f32x4 M;
#pragma unroll
        for (int h = 0; h < 4; h++) {
            float t0 = gm[h] + edv[h];
            M[h] = (t0 > 0.f) ? t0 : 0.2f * t0;
        }
        f32x4 dsum = (f32x4){0.f, 0.f, 0.f, 0.f};
        f32x2 acc2[4];
#pragma unroll
        for (int d = 0; d < 4; d++) acc2[d] = (f32x2){0.f, 0.f};
        for (int c0 = 0; c0 < deg; c0 += 64) {
            int cn = min(deg - c0, 64);
            int s = 0;
            f32x4 pv = (f32x4){0.f, 0.f, 0.f, 0.f};
            if (l < cn) {
                s = csr[base + c0 + l];
                f32x4 e = *reinterpret_cast<const f32x4*>(es4 + (size_t)s * 4);
#pragma unroll
                for (int h = 0; h < 4; h++) {
                    float t = e[h] + edv[h];
                    t = (t > 0.f) ? t : 0.2f * t;
                    pv[h] = __expf(t - M[h]);
                }
            }
            sw[l] = s;
#pragma unroll
            for (int h = 0; h < 4; h++) pw[h * 64 + l] = pv[h];
#pragma unroll
            for (int h = 0; h < 4; h++) dsum[h] += pv[h];
            int jn = (cn + 15) & ~15;
            for (int j = 0; j < jn; j += 16) {
                int e0 = j + 8 * half;
                s32x4 sA = *reinterpret_cast<const s32x4*>(&sw[e0]);
                s32x4 sB = *reinterpret_cast<const s32x4*>(&sw[e0 + 4]);
                f32x4 pA = *reinterpret_cast<const f32x4*>(&pw[hd8 * 64 + e0]);
                f32x4 pB = *reinterpret_cast<const f32x4*>(&pw[hd8 * 64 + e0 + 4]);
                u32x4 hv[8];
#pragma unroll
                for (int i = 0; i < 8; i++) {
                    int sj = (i < 4) ? sA[i & 3] : sB[i & 3];
                    hv[i] = *reinterpret_cast<const u32x4*>(Hb + (size_t)sj * HC + hl * 8);
                }
#pragma unroll
                for (int i = 0; i < 8; i++) {
                    float p = (i < 4) ? pA[i & 3] : pB[i & 3];
#pragma unroll
                    for (int d = 0; d < 4; d++) {
                        unsigned int u = hv[i][d];
                        f32x2 h2;
                        h2.x = __uint_as_float(u << 16);
                        h2.y = __uint_as_float(u & 0xFFFF0000u);
                        acc2[d] += h2 * p;
                    }
                }
            }
        }
#pragma unroll
        for (int o = 32; o; o >>= 1)
#pragma unroll
            for (int h = 0; h < 4; h++) dsum[h] += __shfl_xor(dsum[h], o);
#pragma unroll
        for (int d = 0; d < 4; d++) {
            acc2[d].x += __shfl_xor(acc2[d].x, 32);
            acc2[d].y += __shfl_xor(acc2[d].y, 32);
        }
        float rinv = 1.0f / fmaxf(dsum[hd8], 1e-16f);
        if (half == 0) {
            bf16x8 ov;
#pragma unroll
            for (int d = 0; d < 4; d++) {
                float v0 = acc2[d].x * rinv + ldf(bias, (size_t)hl * 8 + 2 * d, bf);
                float v1 = acc2[d].y * rinv + ldf(bias, (size_t)hl * 8 + 2 * d + 1, bf);
                ov[2 * d]     = f2bs(fmaxf(v0, 0.f));
                ov[2 * d + 1] = f2bs(fmaxf(v1, 0.f));
            }
            *reinterpret_cast<bf16x8*>(out + (size_t)n * HC + hl * 8) = ov;
        }
    }
}

// ================= L3: agg layer-1 || gemm layer-2 (waits on agg1) =================
__global__ __launch_bounds__(256) void k_p3(const void* __restrict__ x,
                                            const __hip_bfloat16* __restrict__ hb,
                                            __hip_bfloat16* __restrict__ hb_mut,
                                            const float* __restrict__ es, const float* __restrict__ ed,
                                            float* __restrict__ es_mut, float* __restrict__ ed_mut,
                                            const void* __restrict__ b1,
                                            const int* __restrict__ off, const int* __restrict__ csr,
                                            unsigned* __restrict__ gp2,
                                            __hip_bfloat16* __restrict__ xb,
                                            const __hip_bfloat16* __restrict__ Wt2,
                                            const void* __restrict__ as2, const void* __restrict__ ad2,
                                            int* __restrict__ sy) {
    __shared__ int smem[2048];  // 8 KB
    int bid = blockIdx.x;
    int bf = probe_xbf((const unsigned int*)x);
    if (bid < ABLK) {
        dev_agg(bid * 4, hb, es, ed, b1, off, csr, gp2, bf, xb, smem);
        signal_done(&sy[2]);
    } else {
        spin_wait(&sy[2], ABLK);  // all xb written
        int t0 = bid - ABLK;
        dev_gemm(t0, xb, Wt2, hb_mut, as2, ad2, es_mut, ed_mut, gp2, bf, 1, (u32x4*)smem);
        dev_gemm(t0 + G2BLK, xb, Wt2, hb_mut, as2, ad2, es_mut, ed_mut, gp2, bf, 1, (u32x4*)smem);
    }
}

// ================= L4: agg layer-2 || groupsum (waits) || final (waits) =================
__global__ __launch_bounds__(256) void k_p4(const void* __restrict__ x,
                                            const int* __restrict__ ei,
                                            const __hip_bfloat16* __restrict__ hb,
                                            const float* __restrict__ es, const float* __restrict__ ed,
                                            const void* __restrict__ b2,
                                            const int* __restrict__ off, const int* __restrict__ csr,
                                            const unsigned* __restrict__ gp2,
                                            __hip_bfloat16* __restrict__ xb2,
                                            const int* __restrict__ bat,
                                            float* __restrict__ sx, const int* __restrict__ cnt,
                                            const void* __restrict__ Wp, const void* __restrict__ bp,
                                            void* __restrict__ out, int* __restrict__ sy) {
    __shared__ int smem[2048];
    int bid = blockIdx.x, t = threadIdx.x;
    if (bid < ABLK) {
        int bf = probe_xbf((const unsigned int*)x);
        dev_agg(bid * 4, hb, es, ed, b2, off, csr, gp2, bf, xb2, smem);
        signal_done(&sy[3]);
    } else if (bid < ABLK + 250) {
        // groupsum: 4-row-parallel boundary-flush
        int f = probe_edge64(ei);
        spin_wait(&sy[3], ABLK);
        const int RPB = NNODES / 250;  // 80
        int b = bid - ABLK;
        int sub = t >> 6, l = t & 63;
        int r = b * RPB + sub;
        f32x4 acc = (f32x4){0.f, 0.f, 0.f, 0.f};
        int curg = ld_idx(bat, r, f);
        for (int k = 0; k < RPB / 4; k++, r += 4) {
            int g = ld_idx(bat, r, f);
            if (g != curg) {
#pragma unroll
                for (int c = 0; c < 4; c++) atomicAdd(&sx[(size_t)curg * HC + l * 4 + c], acc[c]);
                acc = (f32x4){0.f, 0.f, 0.f, 0.f}; curg = g;
            }
            s16x4 hv = *reinterpret_cast<const s16x4*>(xb2 + (size_t)r * HC + l * 4);
#pragma unroll
            for (int c = 0; c < 4; c++) acc[c] += bs2f(hv[c]);
        }
#pragma unroll
        for (int c = 0; c < 4; c++) atomicAdd(&sx[(size_t)curg * HC + l * 4 + c], acc[c]);
        signal_done(&sy[4]);
    } else {
        // final projection: one block per group
        int bf = probe_xbf((const unsigned int*)x);
        spin_wait(&sy[4], 250);
        float* red = (float*)smem;
        int g = bid - (ABLK + 250);
        int c = t & 31, seg = t >> 5;
        const float* sxg = sx + (size_t)g * HC;
        float a = 0.f;
#pragma unroll
        for (int k = 0; k < 32; k++) {
            int kk = seg * 32 + k;
            a = fmaf(sxg[kk], ldf(Wp, (size_t)kk * DOUT + c, bf), a);
        }
        red[seg * 32 + c] = a;
        __syncthreads();
        if (t < 32) {
            float s = 0.f;
#pragma unroll
            for (int i = 0; i < 8; i++) s += red[i * 32 + t];
            int ct = cnt[g];
            float v = (ct > 0) ? (s / ct + ldf(bp, (size_t)t, bf)) : 0.f;
            if (bf) ((__hip_bfloat16*)out)[g * DOUT + t] = __float2bfloat16(v);
            else    ((float*)out)[g * DOUT + t]          = v;
        }
    }
}

extern "C" void kernel_launch(void* const* d_in, const int* in_sizes, int n_in,
                              void* d_out, int out_size, void* d_ws, size_t ws_size,
                              hipStream_t stream) {
    (void)in_sizes; (void)n_in; (void)out_size; (void)ws_size;
    const void* x   = d_in[0];
    const int*  ei  = (const int*)d_in[1];
    const int*  bat = (const int*)d_in[2];
    const void* W1  = d_in[3];
    const void* as1 = d_in[4];
    const void* ad1 = d_in[5];
    const void* b1  = d_in[6];
    const void* W2  = d_in[7];
    const void* as2 = d_in[8];
    const void* ad2 = d_in[9];
    const void* b2  = d_in[10];
    const void* Wp  = d_in[11];
    const void* bp  = d_in[12];

    char* ws = (char*)d_ws;
    size_t o = 0;
    auto alloc = [&](size_t bytes) -> char* {
        char* p = ws + o;
        o += (bytes + 255) & ~(size_t)255;
        return p;
    };
    __hip_bfloat16* hb  = (__hip_bfloat16*)alloc((size_t)NNODES * HC * 2);
    __hip_bfloat16* xb  = (__hip_bfloat16*)alloc((size_t)NNODES * HC * 2);
    __hip_bfloat16* xb2 = (__hip_bfloat16*)alloc((size_t)NNODES * HC * 2);
    __hip_bfloat16* Wt1 = (__hip_bfloat16*)alloc((size_t)HC * HC * 2);
    __hip_bfloat16* Wt2 = (__hip_bfloat16*)alloc((size_t)HC * HC * 2);
    float* es = (float*)alloc((size_t)NNODES * 4 * 4);
    float* ed = (float*)alloc((size_t)NNODES * 4 * 4);
    int* H    = (int*)alloc((size_t)NBLK * NNODES * 4);
    int* off  = (int*)alloc((size_t)(NNODES + 1) * 4);
    int* csr  = (int*)alloc((size_t)ETOT * 4);
    int* bsum = (int*)alloc((size_t)CBLK * 4);
    unsigned* gp2 = (unsigned*)alloc(256 * 4);
    float* sx = (float*)alloc((size_t)NGROUP * HC * 4);
    int* cnt  = (int*)alloc(256);
    int* sy   = (int*)alloc(256);   // handshake counters

    // 4 launches total
    k_setup<<<NBLK + 512, 256, 0, stream>>>((const unsigned int*)x, ei, bat, W1, W2,
                                            Wt1, Wt2, H, sx, cnt, gp2, sy);
    k_p2<<<CBLK + NBLK + GBLK, 256, 0, stream>>>(x, ei, H, bsum, off, csr, Wt1, hb,
                                                 as1, ad1, es, ed, gp2, sy);
    k_p3<<<ABLK + G2BLK, 256, 0, stream>>>(x, hb, hb, es, ed, es, ed, b1, off, csr,
                                           gp2, xb, Wt2, as2, ad2, sy);
    k_p4<<<ABLK + 250 + NGROUP, 256, 0, stream>>>(x, ei, hb, es, ed, b2, off, csr,
                                                  gp2, xb2, bat, sx, cnt, Wp, bp,
                                                  d_out, sy);
}

// Round 12
// 374.507 us; speedup vs baseline: 2.9899x; 2.9899x over previous
//
#include <hip/hip_runtime.h>
#include <hip/hip_bf16.h>
#include <cstdint>

#define NNODES 20000
#define NEDGES 640000
#define ETOT   (NEDGES + NNODES)
#define NGROUP 64
#define HC     256
#define DOUT   32
#define EBLK   5120                     // edges per CSR slice (divides NEDGES)
#define NBLK   125                      // hist/scatter slices
#define CBLK   79                       // ceil(NNODES/256) node blocks
#define GBLK   1250                     // gemm tiles (16 rows each)
#define ABLK   2500                     // agg blocks

typedef short bf16x8 __attribute__((ext_vector_type(8)));
typedef short s16x4  __attribute__((ext_vector_type(4)));
typedef float f32x4  __attribute__((ext_vector_type(4)));
typedef float f32x2  __attribute__((ext_vector_type(2)));
typedef int   s32x4  __attribute__((ext_vector_type(4)));
typedef unsigned int u32x4 __attribute__((ext_vector_type(4)));

__device__ __forceinline__ float bs2f(short v) {
    union { unsigned int u; float f; } c; c.u = ((unsigned int)(unsigned short)v) << 16; return c.f;
}
__device__ __forceinline__ short f2bs(float v) {
    __hip_bfloat16 b = __float2bfloat16(v);
    union { __hip_bfloat16 b; short s; } u; u.b = b; return u.s;
}
__device__ __forceinline__ float ldf(const void* __restrict__ p, size_t i, int bf) {
    return bf ? __bfloat162float(((const __hip_bfloat16*)p)[i]) : ((const float*)p)[i];
}
__device__ __forceinline__ int ld_idx(const int* __restrict__ p, size_t i, int f64) {
    return f64 ? p[2 * i] : p[i];
}
// monotone float<->uint map for atomicMax on floats
__device__ __forceinline__ unsigned enc_f(float f) {
    unsigned u = __float_as_uint(f);
    return (u >> 31) ? ~u : (u | 0x80000000u);
}
__device__ __forceinline__ float dec_f(unsigned e) {
    return (e >> 31) ? __uint_as_float(e & 0x7FFFFFFFu) : __uint_as_float(~e);
}
// local flag probes (identical result in every block -> no flag round-trip)
__device__ __forceinline__ int probe_edge64(const int* __restrict__ ei) {
    int l = threadIdx.x & 63;
    int zeros = 0;
#pragma unroll
    for (int r = 0; r < 4; r++)
        zeros += __popcll(__ballot(ei[2 * (r * 64 + l) + 1] == 0));
    return (zeros > 200) ? 1 : 0;
}
__device__ __forceinline__ int probe_xbf(const unsigned int* __restrict__ xw) {
    int l = threadIdx.x & 63;
    int ones = 0;
#pragma unroll
    for (int r = 0; r < 4; r++)
        ones += __popcll(__ballot((xw[r * 64 + l] >> 14) & 1));
    return (ones < 64) ? 1 : 0;
}
// ---- SMALL-SCALE producer/consumer handshake (<=250 signalers proven safe;
// 2500-signaler scale is catastrophic — R11's 470us k_p3) ----
__device__ __forceinline__ void signal_done(int* ctr) {
    __threadfence();
    __syncthreads();
    if (threadIdx.x == 0) atomicAdd(ctr, 1);
}
__device__ __forceinline__ void spin_wait(int* ctr, int target) {
    if (threadIdx.x == 0) {
        while (__hip_atomic_load(ctr, __ATOMIC_RELAXED, __HIP_MEMORY_SCOPE_AGENT) < target)
            __builtin_amdgcn_s_sleep(8);
    }
    __syncthreads();
    __threadfence();
}

// ================= L1 setup: hist slices + weight transposes + inits =================
__global__ __launch_bounds__(256) void k_setup(const unsigned int* __restrict__ xw,
                                               const int* __restrict__ ei,
                                               const int* __restrict__ bat,
                                               const void* __restrict__ W1, const void* __restrict__ W2,
                                               __hip_bfloat16* __restrict__ Wt1,
                                               __hip_bfloat16* __restrict__ Wt2,
                                               int* __restrict__ H,
                                               float* __restrict__ sx, int* __restrict__ cnt,
                                               unsigned* __restrict__ gp2, int* __restrict__ sy) {
    __shared__ int hl[NNODES];  // 80 KB
    int t = threadIdx.x, b = blockIdx.x;
    if (b < NBLK) {
        int f = probe_edge64(ei);
        s32x4* hl4 = reinterpret_cast<s32x4*>(hl);
        for (int i = t; i < NNODES / 4; i += 256) hl4[i] = (s32x4){0, 0, 0, 0};
        __syncthreads();
        int s0 = b * EBLK;
        if (f) {
            const int* d64 = ei + 2 * NEDGES;   // low words at d64[2*i]
            for (int i0 = s0; i0 < s0 + EBLK; i0 += 512) {
                int i = i0 + 2 * t;
                s32x4 v = *reinterpret_cast<const s32x4*>(d64 + 2 * (size_t)i);
                atomicAdd(&hl[v[0]], 1);
                atomicAdd(&hl[v[2]], 1);
            }
        } else {
            const int* d32 = ei + NEDGES;
            for (int i0 = s0; i0 < s0 + EBLK; i0 += 1024) {
                int i = i0 + 4 * t;
                s32x4 v = *reinterpret_cast<const s32x4*>(d32 + i);
                atomicAdd(&hl[v[0]], 1); atomicAdd(&hl[v[1]], 1);
                atomicAdd(&hl[v[2]], 1); atomicAdd(&hl[v[3]], 1);
            }
        }
        __syncthreads();
        s32x4* Hb4 = reinterpret_cast<s32x4*>(H + (size_t)b * NNODES);
        for (int i = t; i < NNODES / 4; i += 256) Hb4[i] = hl4[i];
    } else {
        int bf = probe_xbf(xw);
        int i = (b - NBLK) * 256 + t;  // 131072
        int which = i >> 16;
        int j = i & 65535;
        int k = j >> 8, n = j & 255;
        const void* W = which ? W2 : W1;
        __hip_bfloat16* Wt = which ? Wt2 : Wt1;
        Wt[(size_t)n * 256 + k] = __float2bfloat16(ldf(W, (size_t)k * 256 + n, bf));
        if (b == NBLK) {
            for (int q = t; q < NGROUP * HC; q += 256) sx[q] = 0.f;
            if (t < 256) gp2[t] = 0x007FFFFFu;   // enc(-inf), 4 heads x 64 slots
            if (t < 8) sy[t] = 0;                // handshake counters
            // per-group node counts via LDS histogram (batch sorted; order free)
            int f = probe_edge64(ei);
            if (t < NGROUP) hl[t] = 0;
            __syncthreads();
            for (int r = t; r < NNODES; r += 256) atomicAdd(&hl[ld_idx(bat, r, f)], 1);
            __syncthreads();
            if (t < NGROUP) cnt[t] = hl[t];
        }
    }
}

// one 16-row GEMM tile (4 waves; wave w = head w's 64 cols); fused es/ed scores;
// per-head max -> scattered atomicMax tree gp2[w*64 + tile&63].
__device__ __forceinline__ void dev_gemm(int tile, const void* __restrict__ A,
                                         const __hip_bfloat16* __restrict__ Bt,
                                         __hip_bfloat16* __restrict__ Hout,
                                         const void* __restrict__ a_src, const void* __restrict__ a_dst,
                                         float* __restrict__ es4, float* __restrict__ ed4,
                                         unsigned* __restrict__ gp2, int bf, int abf,
                                         u32x4* hst4) {
    int w    = threadIdx.x >> 6;
    int lane = threadIdx.x & 63;
    int mr   = lane & 15;
    int quad = lane >> 4;
    int r0   = tile * 16;
    f32x4 acc[4];
#pragma unroll
    for (int j = 0; j < 4; j++) acc[j] = (f32x4){0.f, 0.f, 0.f, 0.f};
    size_t rowoff = (size_t)(r0 + mr) * HC;
    const __hip_bfloat16* Btw = Bt + (size_t)w * 64 * HC;
    for (int kk = 0; kk < HC; kk += 32) {
        bf16x8 a;
        if (abf) {
            a = *reinterpret_cast<const bf16x8*>((const __hip_bfloat16*)A + rowoff + kk + quad * 8);
        } else {
            const float* af = (const float*)A + rowoff + kk + quad * 8;
            f32x4 lo = *reinterpret_cast<const f32x4*>(af);
            f32x4 hi = *reinterpret_cast<const f32x4*>(af + 4);
#pragma unroll
            for (int ii = 0; ii < 4; ii++) { a[ii] = f2bs(lo[ii]); a[ii + 4] = f2bs(hi[ii]); }
        }
#pragma unroll
        for (int j = 0; j < 4; j++) {
            bf16x8 b = *reinterpret_cast<const bf16x8*>(Btw + (size_t)(j * 16 + mr) * HC + kk + quad * 8);
            acc[j] = __builtin_amdgcn_mfma_f32_16x16x32_bf16(a, b, acc[j], 0, 0, 0);
        }
    }
    short* hst = reinterpret_cast<short*>(hst4);
#pragma unroll
    for (int j = 0; j < 4; j++)
#pragma unroll
        for (int r = 0; r < 4; r++)
            hst[(quad * 4 + r) * HC + w * 64 + j * 16 + mr] = f2bs(acc[j][r]);
    float ps[4] = {0.f, 0.f, 0.f, 0.f}, pd[4] = {0.f, 0.f, 0.f, 0.f};
#pragma unroll
    for (int j = 0; j < 4; j++) {
        float asv = ldf(a_src, (size_t)(w * 64 + j * 16 + mr), bf);
        float adv = ldf(a_dst, (size_t)(w * 64 + j * 16 + mr), bf);
#pragma unroll
        for (int r = 0; r < 4; r++) {
            ps[r] = fmaf(acc[j][r], asv, ps[r]);
            pd[r] = fmaf(acc[j][r], adv, pd[r]);
        }
    }
#pragma unroll
    for (int o = 1; o < 16; o <<= 1)
#pragma unroll
        for (int r = 0; r < 4; r++) {
            ps[r] += __shfl_xor(ps[r], o);
            pd[r] += __shfl_xor(pd[r], o);
        }
    float pm = fmaxf(fmaxf(ps[0], ps[1]), fmaxf(ps[2], ps[3]));
    pm = fmaxf(pm, __shfl_xor(pm, 16));
    pm = fmaxf(pm, __shfl_xor(pm, 32));
    if (lane == 0) atomicMax(&gp2[w * 64 + (tile & 63)], enc_f(pm));
    if (mr == 0)
#pragma unroll
        for (int r = 0; r < 4; r++) {
            int row = r0 + quad * 4 + r;
            es4[(size_t)row * 4 + w] = ps[r];
            ed4[(size_t)row * 4 + w] = pd[r];
        }
    __syncthreads();
    u32x4* dst = reinterpret_cast<u32x4*>((short*)Hout + (size_t)r0 * HC);
    dst[threadIdx.x]       = hst4[threadIdx.x];
    dst[threadIdx.x + 256] = hst4[threadIdx.x + 256];
}

// ================= L2: colsum+base (79-blk handshake) || scatter (waits) || gemm-L1 =====
// Scatter uses GLOBAL atomics on its private H row -> 8 KB LDS only -> gemm keeps
// full occupancy. All 1454 blocks co-resident (cap 2048) -> deadlock-impossible.
__global__ __launch_bounds__(256) void k_p2(const void* __restrict__ x,
                                            const int* __restrict__ ei,
                                            int* __restrict__ H, int* __restrict__ bsum,
                                            int* __restrict__ off, int* __restrict__ csr,
                                            const __hip_bfloat16* __restrict__ Wt1,
                                            __hip_bfloat16* __restrict__ hb,
                                            const void* __restrict__ as1, const void* __restrict__ ad1,
                                            float* __restrict__ es, float* __restrict__ ed,
                                            unsigned* __restrict__ gp2, int* __restrict__ sy) {
    __shared__ int smem[2048];  // 8 KB: gemm hst4 / cb scratch
    int bid = blockIdx.x, t = threadIdx.x;
    if (bid < CBLK) {
        // ---- colsum (deg kept in registers across the handshake) ----
        int n = bid * 256 + t;
        int lane = t & 63, w = t >> 6;
        int d = 0;
        if (n < NNODES) {
#pragma unroll 5
            for (int b = 0; b < NBLK; b++) d += H[(size_t)b * NNODES + n];
            d += 1;  // self-loop
        }
        int r = d;
#pragma unroll
        for (int o = 1; o < 64; o <<= 1) r += __shfl_xor(r, o);
        if (lane == 0) smem[w] = r;
        __syncthreads();
        if (t == 0) bsum[bid] = smem[0] + smem[1] + smem[2] + smem[3];
        signal_done(&sy[0]);
        spin_wait(&sy[0], CBLK);
        // ---- base ----
        int sc = d;
#pragma unroll
        for (int o = 1; o < 64; o <<= 1) {
            int u = __shfl_up(sc, o);
            if (lane >= o) sc += u;
        }
        if (lane == 63) smem[w] = sc;
        if (w == 0) {  // exclusive prefix of block sums
            int v = (lane < bid) ? bsum[lane] : 0;
            if (lane + 64 < bid) v += bsum[lane + 64];
#pragma unroll
            for (int o = 1; o < 64; o <<= 1) v += __shfl_xor(v, o);
            if (lane == 0) smem[4] = v;
        }
        __syncthreads();
        int woff = 0;
        for (int i = 0; i < w; i++) woff += smem[i];
        int excl = woff + sc - d;
        if (bid == 0 && t == 0) off[NNODES] = ETOT;
        if (n < NNODES) {
            int o0 = smem[4] + excl;
            off[n] = o0;
            csr[o0] = n;          // self-loop first
            int run = o0 + 1;
#pragma unroll 5
            for (int b = 0; b < NBLK; b++) {
                size_t idx = (size_t)b * NNODES + n;
                int tt = H[idx];
                H[idx] = run;
                run += tt;
            }
        }
        signal_done(&sy[1]);
    } else if (bid < CBLK + NBLK) {
        // ---- scatter: global atomics on private H row (no LDS) ----
        int b = bid - CBLK;
        int f = probe_edge64(ei);
        spin_wait(&sy[1], CBLK);
        int* Hb = H + (size_t)b * NNODES;
        int s0 = b * EBLK;
        if (f) {
            const int* d64 = ei + 2 * NEDGES;
            for (int i0 = s0; i0 < s0 + EBLK; i0 += 512) {
                int i = i0 + 2 * t;
                s32x4 sv = *reinterpret_cast<const s32x4*>(ei + 2 * (size_t)i);
                s32x4 dv = *reinterpret_cast<const s32x4*>(d64 + 2 * (size_t)i);
                int p0 = atomicAdd(&Hb[dv[0]], 1); csr[p0] = sv[0];
                int p1 = atomicAdd(&Hb[dv[2]], 1); csr[p1] = sv[2];
            }
        } else {
            const int* d32 = ei + NEDGES;
            for (int i0 = s0; i0 < s0 + EBLK; i0 += 1024) {
                int i = i0 + 4 * t;
                s32x4 sv = *reinterpret_cast<const s32x4*>(ei + i);
                s32x4 dv = *reinterpret_cast<const s32x4*>(d32 + i);
#pragma unroll
                for (int k = 0; k < 4; k++) {
                    int p = atomicAdd(&Hb[dv[k]], 1); csr[p] = sv[k];
                }
            }
        }
    } else {
        // ---- gemm layer-1 (independent of CSR; no wait) ----
        int bf = probe_xbf((const unsigned int*)x);
        dev_gemm(bid - (CBLK + NBLK), x, Wt1, hb, as1, ad1, es, ed, gp2, bf, bf,
                 (u32x4*)smem);
    }
}

// ================= fused bound-max softmax + aggregation (standalone launch) ==========
__global__ __launch_bounds__(256) void k_agg(const void* __restrict__ x,
                                             const __hip_bfloat16* __restrict__ Hb,
                                             const float* __restrict__ es4, const float* __restrict__ ed4,
                                             const void* __restrict__ bias,
                                             const int* __restrict__ off, const int* __restrict__ csr,
                                             const unsigned* __restrict__ gp2,
                                             __hip_bfloat16* __restrict__ out) {
    __shared__ float p_lds[4][4][64];
    __shared__ int   s_lds[4][64];
    __shared__ float gm_s[4];
    int wv = threadIdx.x >> 6;
    int l  = threadIdx.x & 63;
    int half = l >> 5;
    int hl   = l & 31;
    int hd8  = hl >> 3;
    int bf = probe_xbf((const unsigned int*)x);
    {   // cheap gmax: 64 lanes read head wv's 64 slots (one coalesced 256B read)
        float m = dec_f(gp2[wv * 64 + l]);
#pragma unroll
        for (int o = 32; o; o >>= 1) m = fmaxf(m, __shfl_xor(m, o));
        if (l == 0) gm_s[wv] = m;
    }
    __syncthreads();
    f32x4 gm = (f32x4){gm_s[0], gm_s[1], gm_s[2], gm_s[3]};
    int n0 = blockIdx.x * 4 + wv;
    for (int n = n0; n < NNODES; n += 10000) {
        int base = off[n], deg = off[n + 1] - base;
        f32x4 edv = *reinterpret_cast<const f32x4*>(ed4 + (size_t)n * 4);
        f32x4 M;
#pragma unroll
        for (int h = 0; h < 4; h++) {
            float t0 = gm[h] + edv[h];
            M[h] = (t0 > 0.f) ? t0 : 0.2f * t0;
        }
        f32x4 dsum = (f32x4){0.f, 0.f, 0.f, 0.f};
        f32x2 acc2[4];
#pragma unroll
        for (int d = 0; d < 4; d++) acc2[d] = (f32x2){0.f, 0.f};
        for (int c0 = 0; c0 < deg; c0 += 64) {
            int cn = min(deg - c0, 64);
            int s = 0;
            f32x4 pv = (f32x4){0.f, 0.f, 0.f, 0.f};
            if (l < cn) {
                s = csr[base + c0 + l];
                f32x4 e = *reinterpret_cast<const f32x4*>(es4 + (size_t)s * 4);
#pragma unroll
                for (int h = 0; h < 4; h++) {
                    float t = e[h] + edv[h];
                    t = (t > 0.f) ? t : 0.2f * t;
                    pv[h] = __expf(t - M[h]);
                }
            }
            s_lds[wv][l] = s;
#pragma unroll
            for (int h = 0; h < 4; h++) p_lds[wv][h][l] = pv[h];
#pragma unroll
            for (int h = 0; h < 4; h++) dsum[h] += pv[h];
            int jn = (cn + 15) & ~15;
            for (int j = 0; j < jn; j += 16) {
                int e0 = j + 8 * half;
                s32x4 sA = *reinterpret_cast<const s32x4*>(&s_lds[wv][e0]);
                s32x4 sB = *reinterpret_cast<const s32x4*>(&s_lds[wv][e0 + 4]);
                f32x4 pA = *reinterpret_cast<const f32x4*>(&p_lds[wv][hd8][e0]);
                f32x4 pB = *reinterpret_cast<const f32x4*>(&p_lds[wv][hd8][e0 + 4]);
                u32x4 hv[8];
#pragma unroll
                for (int i = 0; i < 8; i++) {
                    int sj = (i < 4) ? sA[i & 3] : sB[i & 3];
                    hv[i] = *reinterpret_cast<const u32x4*>(Hb + (size_t)sj * HC + hl * 8);
                }
#pragma unroll
                for (int i = 0; i < 8; i++) {
                    float p = (i < 4) ? pA[i & 3] : pB[i & 3];
#pragma unroll
                    for (int d = 0; d < 4; d++) {
                        unsigned int u = hv[i][d];
                        f32x2 h2;
                        h2.x = __uint_as_float(u << 16);
                        h2.y = __uint_as_float(u & 0xFFFF0000u);
                        acc2[d] += h2 * p;
                    }
                }
            }
        }
#pragma unroll
        for (int o = 32; o; o >>= 1)
#pragma unroll
            for (int h = 0; h < 4; h++) dsum[h] += __shfl_xor(dsum[h], o);
#pragma unroll
        for (int d = 0; d < 4; d++) {
            acc2[d].x += __shfl_xor(acc2[d].x, 32);
            acc2[d].y += __shfl_xor(acc2[d].y, 32);
        }
        float rinv = 1.0f / fmaxf(dsum[hd8], 1e-16f);
        if (half == 0) {
            bf16x8 ov;
#pragma unroll
            for (int d = 0; d < 4; d++) {
                float v0 = acc2[d].x * rinv + ldf(bias, (size_t)hl * 8 + 2 * d, bf);
                float v1 = acc2[d].y * rinv + ldf(bias, (size_t)hl * 8 + 2 * d + 1, bf);
                ov[2 * d]     = f2bs(fmaxf(v0, 0.f));
                ov[2 * d + 1] = f2bs(fmaxf(v1, 0.f));
            }
            *reinterpret_cast<bf16x8*>(out + (size_t)n * HC + hl * 8) = ov;
        }
    }
}

__global__ __launch_bounds__(256) void k_gemm2(const void* __restrict__ x,
                                               const __hip_bfloat16* __restrict__ xb,
                                               const __hip_bfloat16* __restrict__ Wt2,
                                               __hip_bfloat16* __restrict__ hb,
                                               const void* __restrict__ as2, const void* __restrict__ ad2,
                                               float* __restrict__ es, float* __restrict__ ed,
                                               unsigned* __restrict__ gp2) {
    __shared__ u32x4 hst4[512];  // 8 KB
    int bf = probe_xbf((const unsigned int*)x);
    dev_gemm(blockIdx.x, xb, Wt2, hb, as2, ad2, es, ed, gp2, bf, 1, hst4);
}

// ================= L6: groupsum (250 signals) || final (64 spinners) =================
__global__ __launch_bounds__(256) void k_gsf(const void* __restrict__ x,
                                             const int* __restrict__ ei,
                                             const __hip_bfloat16* __restrict__ xb2,
                                             const int* __restrict__ bat,
                                             float* __restrict__ sx, const int* __restrict__ cnt,
                                             const void* __restrict__ Wp, const void* __restrict__ bp,
                                             void* __restrict__ out, int* __restrict__ sy) {
    __shared__ float red[256];
    int bid = blockIdx.x, t = threadIdx.x;
    if (bid < 250) {
        int f = probe_edge64(ei);
        const int RPB = NNODES / 250;  // 80
        int sub = t >> 6, l = t & 63;
        int r = bid * RPB + sub;
        f32x4 acc = (f32x4){0.f, 0.f, 0.f, 0.f};
        int curg = ld_idx(bat, r, f);
        for (int k = 0; k < RPB / 4; k++, r += 4) {
            int g = ld_idx(bat, r, f);
            if (g != curg) {
#pragma unroll
                for (int c = 0; c < 4; c++) atomicAdd(&sx[(size_t)curg * HC + l * 4 + c], acc[c]);
                acc = (f32x4){0.f, 0.f, 0.f, 0.f}; curg = g;
            }
            s16x4 hv = *reinterpret_cast<const s16x4*>(xb2 + (size_t)r * HC + l * 4);
#pragma unroll
            for (int c = 0; c < 4; c++) acc[c] += bs2f(hv[c]);
        }
#pragma unroll
        for (int c = 0; c < 4; c++) atomicAdd(&sx[(size_t)curg * HC + l * 4 + c], acc[c]);
        signal_done(&sy[4]);
    } else {
        int bf = probe_xbf((const unsigned int*)x);
        spin_wait(&sy[4], 250);
        int g = bid - 250;
        int c = t & 31, seg = t >> 5;
        const float* sxg = sx + (size_t)g * HC;
        float a = 0.f;
#pragma unroll
        for (int k = 0; k < 32; k++) {
            int kk = seg * 32 + k;
            a = fmaf(sxg[kk], ldf(Wp, (size_t)kk * DOUT + c, bf), a);
        }
        red[seg * 32 + c] = a;
        __syncthreads();
        if (t < 32) {
            float s = 0.f;
#pragma unroll
            for (int i = 0; i < 8; i++) s += red[i * 32 + t];
            int ct = cnt[g];
            float v = (ct > 0) ? (s / ct + ldf(bp, (size_t)t, bf)) : 0.f;
            if (bf) ((__hip_bfloat16*)out)[g * DOUT + t] = __float2bfloat16(v);
            else    ((float*)out)[g * DOUT + t]          = v;
        }
    }
}

extern "C" void kernel_launch(void* const* d_in, const int* in_sizes, int n_in,
                              void* d_out, int out_size, void* d_ws, size_t ws_size,
                              hipStream_t stream) {
    (void)in_sizes; (void)n_in; (void)out_size; (void)ws_size;
    const void* x   = d_in[0];
    const int*  ei  = (const int*)d_in[1];
    const int*  bat = (const int*)d_in[2];
    const void* W1  = d_in[3];
    const void* as1 = d_in[4];
    const void* ad1 = d_in[5];
    const void* b1  = d_in[6];
    const void* W2  = d_in[7];
    const void* as2 = d_in[8];
    const void* ad2 = d_in[9];
    const void* b2  = d_in[10];
    const void* Wp  = d_in[11];
    const void* bp  = d_in[12];

    char* ws = (char*)d_ws;
    size_t o = 0;
    auto alloc = [&](size_t bytes) -> char* {
        char* p = ws + o;
        o += (bytes + 255) & ~(size_t)255;
        return p;
    };
    __hip_bfloat16* hb  = (__hip_bfloat16*)alloc((size_t)NNODES * HC * 2);
    __hip_bfloat16* xb  = (__hip_bfloat16*)alloc((size_t)NNODES * HC * 2);
    __hip_bfloat16* xb2 = (__hip_bfloat16*)alloc((size_t)NNODES * HC * 2);
    __hip_bfloat16* Wt1 = (__hip_bfloat16*)alloc((size_t)HC * HC * 2);
    __hip_bfloat16* Wt2 = (__hip_bfloat16*)alloc((size_t)HC * HC * 2);
    float* es = (float*)alloc((size_t)NNODES * 4 * 4);
    float* ed = (float*)alloc((size_t)NNODES * 4 * 4);
    int* H    = (int*)alloc((size_t)NBLK * NNODES * 4);
    int* off  = (int*)alloc((size_t)(NNODES + 1) * 4);
    int* csr  = (int*)alloc((size_t)ETOT * 4);
    int* bsum = (int*)alloc((size_t)CBLK * 4);
    unsigned* gp2 = (unsigned*)alloc(256 * 4);
    float* sx = (float*)alloc((size_t)NGROUP * HC * 4);
    int* cnt  = (int*)alloc(256);
    int* sy   = (int*)alloc(256);   // handshake counters

    // 6 launches; only small-scale handshakes (79/125/250 blocks) inside kernels
    k_setup<<<NBLK + 512, 256, 0, stream>>>((const unsigned int*)x, ei, bat, W1, W2,
                                            Wt1, Wt2, H, sx, cnt, gp2, sy);
    k_p2<<<CBLK + NBLK + GBLK, 256, 0, stream>>>(x, ei, H, bsum, off, csr, Wt1, hb,
                                                 as1, ad1, es, ed, gp2, sy);
    k_agg<<<ABLK, 256, 0, stream>>>(x, hb, es, ed, b1, off, csr, gp2, xb);
    k_gemm2<<<GBLK, 256, 0, stream>>>(x, xb, Wt2, hb, as2, ad2, es, ed, gp2);
    k_agg<<<ABLK, 256, 0, stream>>>(x, hb, es, ed, b2, off, csr, gp2, xb2);
    k_gsf<<<250 + NGROUP, 256, 0, stream>>>(x, ei, xb2, bat, sx, cnt, Wp, bp,
                                            d_out, sy);
}

// Round 13
// 328.078 us; speedup vs baseline: 3.4130x; 1.1415x over previous
//
#include <hip/hip_runtime.h>
#include <hip/hip_bf16.h>
#include <cstdint>

#define NNODES 20000
#define NEDGES 640000
#define ETOT   (NEDGES + NNODES)
#define NGROUP 64
#define HC     256
#define DOUT   32
#define EBLK   5120                     // edges per CSR slice (divides NEDGES)
#define NBLK   125                      // hist/scatter slices
#define GBLK   1250                     // gemm tiles (16 rows each)
#define ABLK   2500                     // agg blocks
#define SBLK   313                      // ceil(NNODES/64) cs/b2 blocks

typedef short bf16x8 __attribute__((ext_vector_type(8)));
typedef short s16x4  __attribute__((ext_vector_type(4)));
typedef float f32x4  __attribute__((ext_vector_type(4)));
typedef float f32x2  __attribute__((ext_vector_type(2)));
typedef int   s32x4  __attribute__((ext_vector_type(4)));
typedef unsigned int u32x4 __attribute__((ext_vector_type(4)));

__device__ __forceinline__ float bs2f(short v) {
    union { unsigned int u; float f; } c; c.u = ((unsigned int)(unsigned short)v) << 16; return c.f;
}
__device__ __forceinline__ short f2bs(float v) {
    __hip_bfloat16 b = __float2bfloat16(v);
    union { __hip_bfloat16 b; short s; } u; u.b = b; return u.s;
}
__device__ __forceinline__ float ldf(const void* __restrict__ p, size_t i, int bf) {
    return bf ? __bfloat162float(((const __hip_bfloat16*)p)[i]) : ((const float*)p)[i];
}
__device__ __forceinline__ int ld_idx(const int* __restrict__ p, size_t i, int f64) {
    return f64 ? p[2 * i] : p[i];
}
// monotone float<->uint map for atomicMax on floats
__device__ __forceinline__ unsigned enc_f(float f) {
    unsigned u = __float_as_uint(f);
    return (u >> 31) ? ~u : (u | 0x80000000u);
}
__device__ __forceinline__ float dec_f(unsigned e) {
    return (e >> 31) ? __uint_as_float(e & 0x7FFFFFFFu) : __uint_as_float(~e);
}
// local flag probes (identical result in every block -> no flag round-trip)
__device__ __forceinline__ int probe_edge64(const int* __restrict__ ei) {
    int l = threadIdx.x & 63;
    int zeros = 0;
#pragma unroll
    for (int r = 0; r < 4; r++)
        zeros += __popcll(__ballot(ei[2 * (r * 64 + l) + 1] == 0));
    return (zeros > 200) ? 1 : 0;
}
__device__ __forceinline__ int probe_xbf(const unsigned int* __restrict__ xw) {
    int l = threadIdx.x & 63;
    int ones = 0;
#pragma unroll
    for (int r = 0; r < 4; r++)
        ones += __popcll(__ballot((xw[r * 64 + l] >> 14) & 1));
    return (ones < 64) ? 1 : 0;
}
// small-scale handshake (<=250 signalers proven; 2500 catastrophic — R11)
__device__ __forceinline__ void signal_done(int* ctr) {
    __threadfence();
    __syncthreads();
    if (threadIdx.x == 0) atomicAdd(ctr, 1);
}
__device__ __forceinline__ void spin_wait(int* ctr, int target) {
    if (threadIdx.x == 0) {
        while (__hip_atomic_load(ctr, __ATOMIC_RELAXED, __HIP_MEMORY_SCOPE_AGENT) < target)
            __builtin_amdgcn_s_sleep(8);
    }
    __syncthreads();
    __threadfence();
}

// ================= L1 setup: hist slices + weight transposes + inits =================
__global__ __launch_bounds__(256) void k_setup(const unsigned int* __restrict__ xw,
                                               const int* __restrict__ ei,
                                               const int* __restrict__ bat,
                                               const void* __restrict__ W1, const void* __restrict__ W2,
                                               __hip_bfloat16* __restrict__ Wt1,
                                               __hip_bfloat16* __restrict__ Wt2,
                                               int* __restrict__ H,
                                               float* __restrict__ sx, int* __restrict__ cnt,
                                               unsigned* __restrict__ gp2, int* __restrict__ sy) {
    __shared__ int hl[NNODES];  // 80 KB
    int t = threadIdx.x, b = blockIdx.x;
    if (b < NBLK) {
        int f = probe_edge64(ei);
        s32x4* hl4 = reinterpret_cast<s32x4*>(hl);
        for (int i = t; i < NNODES / 4; i += 256) hl4[i] = (s32x4){0, 0, 0, 0};
        __syncthreads();
        int s0 = b * EBLK;
        if (f) {
            const int* d64 = ei + 2 * NEDGES;   // low words at d64[2*i]
            for (int i0 = s0; i0 < s0 + EBLK; i0 += 512) {
                int i = i0 + 2 * t;
                s32x4 v = *reinterpret_cast<const s32x4*>(d64 + 2 * (size_t)i);
                atomicAdd(&hl[v[0]], 1);
                atomicAdd(&hl[v[2]], 1);
            }
        } else {
            const int* d32 = ei + NEDGES;
            for (int i0 = s0; i0 < s0 + EBLK; i0 += 1024) {
                int i = i0 + 4 * t;
                s32x4 v = *reinterpret_cast<const s32x4*>(d32 + i);
                atomicAdd(&hl[v[0]], 1); atomicAdd(&hl[v[1]], 1);
                atomicAdd(&hl[v[2]], 1); atomicAdd(&hl[v[3]], 1);
            }
        }
        __syncthreads();
        s32x4* Hb4 = reinterpret_cast<s32x4*>(H + (size_t)b * NNODES);
        for (int i = t; i < NNODES / 4; i += 256) Hb4[i] = hl4[i];
    } else {
        int bf = probe_xbf(xw);
        int i = (b - NBLK) * 256 + t;  // 131072
        int which = i >> 16;
        int j = i & 65535;
        int k = j >> 8, n = j & 255;
        const void* W = which ? W2 : W1;
        __hip_bfloat16* Wt = which ? Wt2 : Wt1;
        Wt[(size_t)n * 256 + k] = __float2bfloat16(ldf(W, (size_t)k * 256 + n, bf));
        if (b == NBLK) {
            for (int q = t; q < NGROUP * HC; q += 256) sx[q] = 0.f;
            if (t < 256) gp2[t] = 0x007FFFFFu;   // enc(-inf), 4 heads x 64 slots
            if (t < 8) sy[t] = 0;                // handshake counters
            // per-group node counts via LDS histogram (batch sorted; order free)
            int f = probe_edge64(ei);
            if (t < NGROUP) hl[t] = 0;
            __syncthreads();
            for (int r = t; r < NNODES; r += 256) atomicAdd(&hl[ld_idx(bat, r, f)], 1);
            __syncthreads();
            if (t < NGROUP) cnt[t] = hl[t];
        }
    }
}

// ================= L2: colsum, 4-way b-split (1250 waves, BW-saturated) =================
// thread (n,g): partial = sum of H[b][n] over b in [g*32, min(g*32+32,NBLK));
// writes S[n][g]; wave 0 forms per-node deg (+1 self-loop) and block sum -> bsum.
__global__ __launch_bounds__(256) void k_cs(const int* __restrict__ H,
                                            int* __restrict__ S, int* __restrict__ bsum) {
    __shared__ int sm[4][64];
    int t = threadIdx.x, blk = blockIdx.x;
    int l = t & 63, g = t >> 6;
    int n = blk * 64 + l;
    int partial = 0;
    if (n < NNODES) {
        int bend = min(g * 32 + 32, NBLK);
#pragma unroll 4
        for (int b = g * 32; b < bend; b++) partial += H[(size_t)b * NNODES + n];
        S[(size_t)n * 4 + g] = partial;
    }
    sm[g][l] = partial;
    __syncthreads();
    if (g == 0) {
        int tot = (n < NNODES) ? (1 + sm[0][l] + sm[1][l] + sm[2][l] + sm[3][l]) : 0;
        int r = tot;
#pragma unroll
        for (int o = 1; o < 64; o <<= 1) r += __shfl_xor(r, o);
        if (l == 0) bsum[blk] = r;
    }
}

// ================= L3: base rewrite, 4-way b-split =================
// Each block self-computes boff (reads <=313 bsums), wave-0 scans deg -> off[n],
// writes self-loop csr entry; thread (n,g) rewrites its 32 H rows with running
// bases starting at off[n] + 1 + prefix(S[n][:g]).
__global__ __launch_bounds__(256) void k_b2(int* __restrict__ H,
                                            const int* __restrict__ S,
                                            const int* __restrict__ bsum,
                                            int* __restrict__ off, int* __restrict__ csr) {
    __shared__ int sm_red[4];
    __shared__ int sm_excl[64];
    __shared__ int sm_boff;
    int t = threadIdx.x, blk = blockIdx.x;
    int l = t & 63, g = t >> 6;
    int n = blk * 64 + l;
    // boff = sum bsum[0..blk)
    int v = 0;
    for (int i = t; i < blk; i += 256) v += bsum[i];
    {
        int r = v;
#pragma unroll
        for (int o = 1; o < 64; o <<= 1) r += __shfl_xor(r, o);
        if (l == 0) sm_red[g] = r;
    }
    // per-thread S and deg
    s32x4 s4 = (s32x4){0, 0, 0, 0};
    if (n < NNODES) s4 = *reinterpret_cast<const s32x4*>(S + (size_t)n * 4);
    int deg = (n < NNODES) ? (1 + s4[0] + s4[1] + s4[2] + s4[3]) : 0;
    __syncthreads();
    if (t == 0) sm_boff = sm_red[0] + sm_red[1] + sm_red[2] + sm_red[3];
    if (g == 0) {  // exclusive scan of deg over this block's 64 nodes
        int sc = deg;
#pragma unroll
        for (int o = 1; o < 64; o <<= 1) {
            int u = __shfl_up(sc, o);
            if (l >= o) sc += u;
        }
        sm_excl[l] = sc - deg;
    }
    __syncthreads();
    int off_n = sm_boff + sm_excl[l];
    if (g == 0 && n < NNODES) {
        off[n] = off_n;
        csr[off_n] = n;   // self-loop first
    }
    if (blk == 0 && t == 0) off[NNODES] = ETOT;
    if (n < NNODES) {
        int pre = 1;      // reserve self-loop slot
        if (g > 0) pre += s4[0];
        if (g > 1) pre += s4[1];
        if (g > 2) pre += s4[2];
        int run = off_n + pre;
        int bend = min(g * 32 + 32, NBLK);
        for (int b = g * 32; b < bend; b++) {
            size_t idx = (size_t)b * NNODES + n;
            int tt = H[idx];
            H[idx] = run;
            run += tt;
        }
    }
}

// one 16-row GEMM tile (4 waves; wave w = head w's 64 cols); fused es/ed scores;
// per-head max -> scattered atomicMax tree gp2[w*64 + tile&63].
__device__ __forceinline__ void dev_gemm(int tile, const void* __restrict__ A,
                                         const __hip_bfloat16* __restrict__ Bt,
                                         __hip_bfloat16* __restrict__ Hout,
                                         const void* __restrict__ a_src, const void* __restrict__ a_dst,
                                         float* __restrict__ es4, float* __restrict__ ed4,
                                         unsigned* __restrict__ gp2, int bf, int abf,
                                         u32x4* hst4) {
    int w    = threadIdx.x >> 6;
    int lane = threadIdx.x & 63;
    int mr   = lane & 15;
    int quad = lane >> 4;
    int r0   = tile * 16;
    f32x4 acc[4];
#pragma unroll
    for (int j = 0; j < 4; j++) acc[j] = (f32x4){0.f, 0.f, 0.f, 0.f};
    size_t rowoff = (size_t)(r0 + mr) * HC;
    const __hip_bfloat16* Btw = Bt + (size_t)w * 64 * HC;
    for (int kk = 0; kk < HC; kk += 32) {
        bf16x8 a;
        if (abf) {
            a = *reinterpret_cast<const bf16x8*>((const __hip_bfloat16*)A + rowoff + kk + quad * 8);
        } else {
            const float* af = (const float*)A + rowoff + kk + quad * 8;
            f32x4 lo = *reinterpret_cast<const f32x4*>(af);
            f32x4 hi = *reinterpret_cast<const f32x4*>(af + 4);
#pragma unroll
            for (int ii = 0; ii < 4; ii++) { a[ii] = f2bs(lo[ii]); a[ii + 4] = f2bs(hi[ii]); }
        }
#pragma unroll
        for (int j = 0; j < 4; j++) {
            bf16x8 b = *reinterpret_cast<const bf16x8*>(Btw + (size_t)(j * 16 + mr) * HC + kk + quad * 8);
            acc[j] = __builtin_amdgcn_mfma_f32_16x16x32_bf16(a, b, acc[j], 0, 0, 0);
        }
    }
    short* hst = reinterpret_cast<short*>(hst4);
#pragma unroll
    for (int j = 0; j < 4; j++)
#pragma unroll
        for (int r = 0; r < 4; r++)
            hst[(quad * 4 + r) * HC + w * 64 + j * 16 + mr] = f2bs(acc[j][r]);
    float ps[4] = {0.f, 0.f, 0.f, 0.f}, pd[4] = {0.f, 0.f, 0.f, 0.f};
#pragma unroll
    for (int j = 0; j < 4; j++) {
        float asv = ldf(a_src, (size_t)(w * 64 + j * 16 + mr), bf);
        float adv = ldf(a_dst, (size_t)(w * 64 + j * 16 + mr), bf);
#pragma unroll
        for (int r = 0; r < 4; r++) {
            ps[r] = fmaf(acc[j][r], asv, ps[r]);
            pd[r] = fmaf(acc[j][r], adv, pd[r]);
        }
    }
#pragma unroll
    for (int o = 1; o < 16; o <<= 1)
#pragma unroll
        for (int r = 0; r < 4; r++) {
            ps[r] += __shfl_xor(ps[r], o);
            pd[r] += __shfl_xor(pd[r], o);
        }
    float pm = fmaxf(fmaxf(ps[0], ps[1]), fmaxf(ps[2], ps[3]));
    pm = fmaxf(pm, __shfl_xor(pm, 16));
    pm = fmaxf(pm, __shfl_xor(pm, 32));
    if (lane == 0) atomicMax(&gp2[w * 64 + (tile & 63)], enc_f(pm));
    if (mr == 0)
#pragma unroll
        for (int r = 0; r < 4; r++) {
            int row = r0 + quad * 4 + r;
            es4[(size_t)row * 4 + w] = ps[r];
            ed4[(size_t)row * 4 + w] = pd[r];
        }
    __syncthreads();
    u32x4* dst = reinterpret_cast<u32x4*>((short*)Hout + (size_t)r0 * HC);
    dst[threadIdx.x]       = hst4[threadIdx.x];
    dst[threadIdx.x + 256] = hst4[threadIdx.x + 256];
}

// ================= L4: scatter (global atomics, no LDS, no spin) || gemm-L1 ===========
__global__ __launch_bounds__(256) void k_sg1(const void* __restrict__ x,
                                             const int* __restrict__ ei,
                                             int* __restrict__ H, int* __restrict__ csr,
                                             const __hip_bfloat16* __restrict__ Wt1,
                                             __hip_bfloat16* __restrict__ hb,
                                             const void* __restrict__ as1, const void* __restrict__ ad1,
                                             float* __restrict__ es, float* __restrict__ ed,
                                             unsigned* __restrict__ gp2) {
    __shared__ u32x4 hst4[512];  // 8 KB (gemm only)
    int bid = blockIdx.x, t = threadIdx.x;
    if (bid < NBLK) {
        int b = bid;
        int f = probe_edge64(ei);
        int* Hb = H + (size_t)b * NNODES;
        int s0 = b * EBLK;
        if (f) {
            const int* d64 = ei + 2 * NEDGES;
            for (int i0 = s0; i0 < s0 + EBLK; i0 += 512) {
                int i = i0 + 2 * t;
                s32x4 sv = *reinterpret_cast<const s32x4*>(ei + 2 * (size_t)i);
                s32x4 dv = *reinterpret_cast<const s32x4*>(d64 + 2 * (size_t)i);
                int p0 = atomicAdd(&Hb[dv[0]], 1); csr[p0] = sv[0];
                int p1 = atomicAdd(&Hb[dv[2]], 1); csr[p1] = sv[2];
            }
        } else {
            const int* d32 = ei + NEDGES;
            for (int i0 = s0; i0 < s0 + EBLK; i0 += 1024) {
                int i = i0 + 4 * t;
                s32x4 sv = *reinterpret_cast<const s32x4*>(ei + i);
                s32x4 dv = *reinterpret_cast<const s32x4*>(d32 + i);
#pragma unroll
                for (int k = 0; k < 4; k++) {
                    int p = atomicAdd(&Hb[dv[k]], 1); csr[p] = sv[k];
                }
            }
        }
    } else {
        int bf = probe_xbf((const unsigned int*)x);
        dev_gemm(bid - NBLK, x, Wt1, hb, as1, ad1, es, ed, gp2, bf, bf, hst4);
    }
}

// ================= fused bound-max softmax + aggregation (standalone launch) ==========
__global__ __launch_bounds__(256) void k_agg(const void* __restrict__ x,
                                             const __hip_bfloat16* __restrict__ Hb,
                                             const float* __restrict__ es4, const float* __restrict__ ed4,
                                             const void* __restrict__ bias,
                                             const int* __restrict__ off, const int* __restrict__ csr,
                                             const unsigned* __restrict__ gp2,
                                             __hip_bfloat16* __restrict__ out) {
    __shared__ float p_lds[4][4][64];
    __shared__ int   s_lds[4][64];
    __shared__ float gm_s[4];
    int wv = threadIdx.x >> 6;
    int l  = threadIdx.x & 63;
    int half = l >> 5;
    int hl   = l & 31;
    int hd8  = hl >> 3;
    int bf = probe_xbf((const unsigned int*)x);
    {   // cheap gmax: 64 lanes read head wv's 64 slots (one coalesced 256B read)
        float m = dec_f(gp2[wv * 64 + l]);
#pragma unroll
        for (int o = 32; o; o >>= 1) m = fmaxf(m, __shfl_xor(m, o));
        if (l == 0) gm_s[wv] = m;
    }
    __syncthreads();
    f32x4 gm = (f32x4){gm_s[0], gm_s[1], gm_s[2], gm_s[3]};
    int n0 = blockIdx.x * 4 + wv;
    for (int n = n0; n < NNODES; n += 10000) {
        int base = off[n], deg = off[n + 1] - base;
        f32x4 edv = *reinterpret_cast<const f32x4*>(ed4 + (size_t)n * 4);
        f32x4 M;
#pragma unroll
        for (int h = 0; h < 4; h++) {
            float t0 = gm[h] + edv[h];
            M[h] = (t0 > 0.f) ? t0 : 0.2f * t0;
        }
        f32x4 dsum = (f32x4){0.f, 0.f, 0.f, 0.f};
        f32x2 acc2[4];
#pragma unroll
        for (int d = 0; d < 4; d++) acc2[d] = (f32x2){0.f, 0.f};
        for (int c0 = 0; c0 < deg; c0 += 64) {
            int cn = min(deg - c0, 64);
            int s = 0;
            f32x4 pv = (f32x4){0.f, 0.f, 0.f, 0.f};
            if (l < cn) {
                s = csr[base + c0 + l];
                f32x4 e = *reinterpret_cast<const f32x4*>(es4 + (size_t)s * 4);
#pragma unroll
                for (int h = 0; h < 4; h++) {
                    float t = e[h] + edv[h];
                    t = (t > 0.f) ? t : 0.2f * t;
                    pv[h] = __expf(t - M[h]);
                }
            }
            s_lds[wv][l] = s;
#pragma unroll
            for (int h = 0; h < 4; h++) p_lds[wv][h][l] = pv[h];
#pragma unroll
            for (int h = 0; h < 4; h++) dsum[h] += pv[h];
            int jn = (cn + 15) & ~15;
            for (int j = 0; j < jn; j += 16) {
                int e0 = j + 8 * half;
                s32x4 sA = *reinterpret_cast<const s32x4*>(&s_lds[wv][e0]);
                s32x4 sB = *reinterpret_cast<const s32x4*>(&s_lds[wv][e0 + 4]);
                f32x4 pA = *reinterpret_cast<const f32x4*>(&p_lds[wv][hd8][e0]);
                f32x4 pB = *reinterpret_cast<const f32x4*>(&p_lds[wv][hd8][e0 + 4]);
                u32x4 hv[8];
#pragma unroll
                for (int i = 0; i < 8; i++) {
                    int sj = (i < 4) ? sA[i & 3] : sB[i & 3];
                    hv[i] = *reinterpret_cast<const u32x4*>(Hb + (size_t)sj * HC + hl * 8);
                }
#pragma unroll
                for (int i = 0; i < 8; i++) {
                    float p = (i < 4) ? pA[i & 3] : pB[i & 3];
#pragma unroll
                    for (int d = 0; d < 4; d++) {
                        unsigned int u = hv[i][d];
                        f32x2 h2;
                        h2.x = __uint_as_float(u << 16);
                        h2.y = __uint_as_float(u & 0xFFFF0000u);
                        acc2[d] += h2 * p;
                    }
                }
            }
        }
#pragma unroll
        for (int o = 32; o; o >>= 1)
#pragma unroll
            for (int h = 0; h < 4; h++) dsum[h] += __shfl_xor(dsum[h], o);
#pragma unroll
        for (int d = 0; d < 4; d++) {
            acc2[d].x += __shfl_xor(acc2[d].x, 32);
            acc2[d].y += __shfl_xor(acc2[d].y, 32);
        }
        float rinv = 1.0f / fmaxf(dsum[hd8], 1e-16f);
        if (half == 0) {
            bf16x8 ov;
#pragma unroll
            for (int d = 0; d < 4; d++) {
                float v0 = acc2[d].x * rinv + ldf(bias, (size_t)hl * 8 + 2 * d, bf);
                float v1 = acc2[d].y * rinv + ldf(bias, (size_t)hl * 8 + 2 * d + 1, bf);
                ov[2 * d]     = f2bs(fmaxf(v0, 0.f));
                ov[2 * d + 1] = f2bs(fmaxf(v1, 0.f));
            }
            *reinterpret_cast<bf16x8*>(out + (size_t)n * HC + hl * 8) = ov;
        }
    }
}

__global__ __launch_bounds__(256) void k_gemm2(const void* __restrict__ x,
                                               const __hip_bfloat16* __restrict__ xb,
                                               const __hip_bfloat16* __restrict__ Wt2,
                                               __hip_bfloat16* __restrict__ hb,
                                               const void* __restrict__ as2, const void* __restrict__ ad2,
                                               float* __restrict__ es, float* __restrict__ ed,
                                               unsigned* __restrict__ gp2) {
    __shared__ u32x4 hst4[512];  // 8 KB
    int bf = probe_xbf((const unsigned int*)x);
    dev_gemm(blockIdx.x, xb, Wt2, hb, as2, ad2, es, ed, gp2, bf, 1, hst4);
}

// ================= L8: groupsum (250 signals) || final (64 spinners) =================
__global__ __launch_bounds__(256) void k_gsf(const void* __restrict__ x,
                                             const int* __restrict__ ei,
                                             const __hip_bfloat16* __restrict__ xb2,
                                             const int* __restrict__ bat,
                                             float* __restrict__ sx, const int* __restrict__ cnt,
                                             const void* __restrict__ Wp, const void* __restrict__ bp,
                                             void* __restrict__ out, int* __restrict__ sy) {
    __shared__ float red[256];
    int bid = blockIdx.x, t = threadIdx.x;
    if (bid < 250) {
        int f = probe_edge64(ei);
        const int RPB = NNODES / 250;  // 80
        int sub = t >> 6, l = t & 63;
        int r = bid * RPB + sub;
        f32x4 acc = (f32x4){0.f, 0.f, 0.f, 0.f};
        int curg = ld_idx(bat, r, f);
        for (int k = 0; k < RPB / 4; k++, r += 4) {
            int g = ld_idx(bat, r, f);
            if (g != curg) {
#pragma unroll
                for (int c = 0; c < 4; c++) atomicAdd(&sx[(size_t)curg * HC + l * 4 + c], acc[c]);
                acc = (f32x4){0.f, 0.f, 0.f, 0.f}; curg = g;
            }
            s16x4 hv = *reinterpret_cast<const s16x4*>(xb2 + (size_t)r * HC + l * 4);
#pragma unroll
            for (int c = 0; c < 4; c++) acc[c] += bs2f(hv[c]);
        }
#pragma unroll
        for (int c = 0; c < 4; c++) atomicAdd(&sx[(size_t)curg * HC + l * 4 + c], acc[c]);
        signal_done(&sy[4]);
    } else {
        int bf = probe_xbf((const unsigned int*)x);
        spin_wait(&sy[4], 250);
        int g = bid - 250;
        int c = t & 31, seg = t >> 5;
        const float* sxg = sx + (size_t)g * HC;
        float a = 0.f;
#pragma unroll
        for (int k = 0; k < 32; k++) {
            int kk = seg * 32 + k;
            a = fmaf(sxg[kk], ldf(Wp, (size_t)kk * DOUT + c, bf), a);
        }
        red[seg * 32 + c] = a;
        __syncthreads();
        if (t < 32) {
            float s = 0.f;
#pragma unroll
            for (int i = 0; i < 8; i++) s += red[i * 32 + t];
            int ct = cnt[g];
            float v = (ct > 0) ? (s / ct + ldf(bp, (size_t)t, bf)) : 0.f;
            if (bf) ((__hip_bfloat16*)out)[g * DOUT + t] = __float2bfloat16(v);
            else    ((float*)out)[g * DOUT + t]          = v;
        }
    }
}

extern "C" void kernel_launch(void* const* d_in, const int* in_sizes, int n_in,
                              void* d_out, int out_size, void* d_ws, size_t ws_size,
                              hipStream_t stream) {
    (void)in_sizes; (void)n_in; (void)out_size; (void)ws_size;
    const void* x   = d_in[0];
    const int*  ei  = (const int*)d_in[1];
    const int*  bat = (const int*)d_in[2];
    const void* W1  = d_in[3];
    const void* as1 = d_in[4];
    const void* ad1 = d_in[5];
    const void* b1  = d_in[6];
    const void* W2  = d_in[7];
    const void* as2 = d_in[8];
    const void* ad2 = d_in[9];
    const void* b2  = d_in[10];
    const void* Wp  = d_in[11];
    const void* bp  = d_in[12];

    char* ws = (char*)d_ws;
    size_t o = 0;
    auto alloc = [&](size_t bytes) -> char* {
        char* p = ws + o;
        o += (bytes + 255) & ~(size_t)255;
        return p;
    };
    __hip_bfloat16* hb  = (__hip_bfloat16*)alloc((size_t)NNODES * HC * 2);
    __hip_bfloat16* xb  = (__hip_bfloat16*)alloc((size_t)NNODES * HC * 2);
    __hip_bfloat16* xb2 = (__hip_bfloat16*)alloc((size_t)NNODES * HC * 2);
    __hip_bfloat16* Wt1 = (__hip_bfloat16*)alloc((size_t)HC * HC * 2);
    __hip_bfloat16* Wt2 = (__hip_bfloat16*)alloc((size_t)HC * HC * 2);
    float* es = (float*)alloc((size_t)NNODES * 4 * 4);
    float* ed = (float*)alloc((size_t)NNODES * 4 * 4);
    int* H    = (int*)alloc((size_t)NBLK * NNODES * 4);
    int* S    = (int*)alloc((size_t)NNODES * 4 * 4);    // per-node 4-group partial sums
    int* off  = (int*)alloc((size_t)(NNODES + 1) * 4);
    int* csr  = (int*)alloc((size_t)ETOT * 4);
    int* bsum = (int*)alloc((size_t)SBLK * 4);
    unsigned* gp2 = (unsigned*)alloc(256 * 4);
    float* sx = (float*)alloc((size_t)NGROUP * HC * 4);
    int* cnt  = (int*)alloc(256);
    int* sy   = (int*)alloc(256);   // handshake counters

    // 8 launches
    k_setup<<<NBLK + 512, 256, 0, stream>>>((const unsigned int*)x, ei, bat, W1, W2,
                                            Wt1, Wt2, H, sx, cnt, gp2, sy);
    k_cs<<<SBLK, 256, 0, stream>>>(H, S, bsum);
    k_b2<<<SBLK, 256, 0, stream>>>(H, S, bsum, off, csr);
    k_sg1<<<NBLK + GBLK, 256, 0, stream>>>(x, ei, H, csr, Wt1, hb, as1, ad1, es, ed, gp2);
    k_agg<<<ABLK, 256, 0, stream>>>(x, hb, es, ed, b1, off, csr, gp2, xb);
    k_gemm2<<<GBLK, 256, 0, stream>>>(x, xb, Wt2, hb, as2, ad2, es, ed, gp2);
    k_agg<<<ABLK, 256, 0, stream>>>(x, hb, es, ed, b2, off, csr, gp2, xb2);
    k_gsf<<<250 + NGROUP, 256, 0, stream>>>(x, ei, xb2, bat, sx, cnt, Wp, bp,
                                            d_out, sy);
}